// Round 10
// baseline (194.710 us; speedup 1.0000x reference)
//
#include <hip/hip_runtime.h>
#include <stdint.h>

// ---------- types ----------
typedef __attribute__((ext_vector_type(8))) __bf16 bf16x8;
typedef __attribute__((ext_vector_type(4))) float f32x4;
typedef __attribute__((ext_vector_type(16))) float f32x16;
typedef __attribute__((ext_vector_type(8))) unsigned short ushort8;

// ---------- helpers ----------
__device__ __forceinline__ unsigned short f2bf(float f){
  union { float f; unsigned int i; } v; v.f = f;
  unsigned int r = v.i + 0x7fffu + ((v.i >> 16) & 1u);   // RNE
  return (unsigned short)(r >> 16);
}
__device__ __forceinline__ void gload16(const void* g, void* l){
  __builtin_amdgcn_global_load_lds((__attribute__((address_space(1))) void*)(g),
                                   (__attribute__((address_space(3))) void*)(l),
                                   16, 0, 0);
}
__device__ __forceinline__ unsigned int cvtpk(float lo, float hi){
  unsigned int r;
  asm("v_cvt_pk_bf16_f32 %0, %1, %2" : "=v"(r) : "v"(lo), "v"(hi));
  return r;
}
// swizzled LDS read of a 16B chunk from a [64][64] bf16 tile (128B rows)
__device__ __forceinline__ bf16x8 ldsw(const char* tile, int row, int colb){
  return *(const bf16x8*)(tile + row*128 + (colb ^ ((row & 7) << 4)));
}

// ---------- constants ----------
#define SEQ   2048
#define DM    1024
#define NH    16
#define DK    64
#define BATCH 4
#define MTOT  (BATCH*SEQ)          // 8192
#define NX    (MTOT*DM)            // 8388608 elements in x
#define NW    (DM*DM)              // 1048576 per weight

#define QSCALE 0.18033688011112f   // (1/8) * log2(e)  -> softmax in exp2 domain

// ============================================================
// sin/cos table: tab[s*32+i] = {cos, sin} of pos[s]*theta^(-2i/64)
// ============================================================
__global__ __launch_bounds__(256) void k_tables(const int* __restrict__ pos,
                                                float* __restrict__ tab)
{
  const int idx = blockIdx.x * 256 + threadIdx.x;    // 65536 total
  const int s = idx >> 5, i = idx & 31;
  const float inv = __expf(-0.28782313662425575f * (float)i);
  const float a = (float)pos[s] * inv;
  tab[2*idx]   = cosf(a);
  tab[2*idx+1] = sinf(a);
}

// ============================================================
// fp32 -> bf16 convert: x (8.4M) then Wq,Wk,Wv,Wo (1M each)
// ============================================================
__global__ __launch_bounds__(256) void k_convert(
    const float* __restrict__ x,  const float* __restrict__ wq,
    const float* __restrict__ wk, const float* __restrict__ wv,
    const float* __restrict__ wo,
    unsigned short* __restrict__ xb, unsigned short* __restrict__ wb)
{
  const long long tid = (long long)blockIdx.x * 256 + threadIdx.x;
  const long long e = tid * 4;
  const float* src; unsigned short* dst;
  if (e < NX) { src = x + e; dst = xb + e; }
  else {
    long long j = e - NX;
    int seg = (int)(j >> 20);            // /1048576
    long long off = j & 1048575;
    src = (seg==0?wq:seg==1?wk:seg==2?wv:wo) + off;
    dst = wb + (size_t)seg*NW + off;
  }
  float4 v = *(const float4*)src;
  unsigned long long pk =  (unsigned long long)f2bf(v.x)
                        | ((unsigned long long)f2bf(v.y) << 16)
                        | ((unsigned long long)f2bf(v.z) << 32)
                        | ((unsigned long long)f2bf(v.w) << 48);
  *(unsigned long long*)dst = pk;
}

// ============================================================
// NT GEMM: C[M=8192][N] = A[M][K=1024] * W[N][K]^T  (bf16 MFMA)
// 256x128 tile, BK=32, 8 waves (4M x 2N), per-wave 64x64 output.
// TRIPLE-buffered global_load_lds staging with COUNTED vmcnt (T4):
// at iter t read buf[t%3], issue stage(t+2) -> buf[(t+2)%3], then
// s_waitcnt vmcnt(3) (leaves the 3 just-issued loads in flight,
// guarantees stage(t+1) complete) + raw s_barrier. Loads span
// barriers -> no per-iteration HBM-latency drain. 72 KB LDS -> 2 blk/CU.
// ============================================================
#define BK 32
#define NTK (DM/BK)   // 32

template<int MODE>
__global__ __launch_bounds__(512, 4) void k_gemm(
    const unsigned short* __restrict__ A,
    const unsigned short* __restrict__ Wb,
    unsigned short* __restrict__ D0,
    unsigned short* __restrict__ D1,
    unsigned short* __restrict__ D2,
    float* __restrict__ Dout,
    const float* __restrict__ tab)
{
  __shared__ __attribute__((aligned(16))) unsigned short As[3][256*BK];  // 48 KB
  __shared__ __attribute__((aligned(16))) unsigned short Bs[3][128*BK];  // 24 KB
  const int tid  = threadIdx.x;
  const int lane = tid & 63;
  const int w    = tid >> 6;          // 0..7
  const int wm = w >> 1, wn = w & 1;  // 4M x 2N
  const int m0 = blockIdx.x * 256;
  const int n0 = blockIdx.y * 128;

  const int z = (MODE == 0) ? blockIdx.z : 0;
  const unsigned short* W = Wb + (size_t)z * NW;
  unsigned short* Dh = (MODE == 0) ? ((z == 0) ? D0 : (z == 1) ? D1 : D2) : nullptr;
  const bool vtr = (MODE == 0) && (z == 2);

  f32x4 acc[4][4];
  #pragma unroll
  for (int i = 0; i < 4; ++i)
    #pragma unroll
    for (int j = 0; j < 4; ++j)
      acc[i][j] = (f32x4)0.0f;

  auto stage = [&](int buf, int t){   // 3 gload16 per thread
    const int k0 = t * BK;
    #pragma unroll
    for (int cc = 0; cc < 2; ++cc){
      const int f = cc*512 + tid;
      const int row = f >> 2, kc = f & 3;
      gload16(A + (size_t)(m0 + row)*DM + k0 + kc*8,
              (char*)&As[buf][0] + (cc*512 + w*64)*16);
    }
    {
      const int row = tid >> 2, kc = tid & 3;
      gload16(W + (size_t)(n0 + row)*DM + k0 + kc*8,
              (char*)&Bs[buf][0] + (w*64)*16);
    }
  };

  // prologue: fill buf0, buf1; wait for buf0 (oldest 3 of 6 in flight)
  stage(0, 0);
  stage(1, 1);
  asm volatile("s_waitcnt vmcnt(3)" ::: "memory");
  __builtin_amdgcn_s_barrier();

  int rb = 0, wbuf = 2;
  for (int t = 0; t < NTK; ++t){
    if (t + 2 < NTK) stage(wbuf, t + 2);      // issue-early: overlaps this iter's compute
    const char* Ab_ = (const char*)&As[rb][0];
    const char* Bb_ = (const char*)&Bs[rb][0];
    bf16x8 af[4], bfr[4];
    #pragma unroll
    for (int i = 0; i < 4; ++i){
      af[i]  = *(const bf16x8*)(Ab_ + (wm*64 + i*16 + (lane & 15))*64 + ((lane >> 4) << 4));
      bfr[i] = *(const bf16x8*)(Bb_ + (wn*64 + i*16 + (lane & 15))*64 + ((lane >> 4) << 4));
    }
    #pragma unroll
    for (int i = 0; i < 4; ++i)
      #pragma unroll
      for (int j = 0; j < 4; ++j)
        acc[i][j] = __builtin_amdgcn_mfma_f32_16x16x32_bf16(af[i], bfr[j], acc[i][j], 0, 0, 0);
    // counted wait: stage(t+1) (issued last iter) must be done; the 3
    // newest (stage t+2, just issued) stay in flight across the barrier.
    if (t + 2 < NTK) asm volatile("s_waitcnt vmcnt(3)" ::: "memory");
    else             asm volatile("s_waitcnt vmcnt(0)" ::: "memory");
    __builtin_amdgcn_s_barrier();
    rb   = (rb   == 2) ? 0 : rb + 1;
    wbuf = (wbuf == 2) ? 0 : wbuf + 1;
  }

  // epilogue: C row = (lane>>4)*4+r, col = lane&15 (verified m89/m91 layout)
  if (MODE == 0 && !vtr){
    const float scale = (z == 0) ? QSCALE : 1.0f;
    #pragma unroll
    for (int i = 0; i < 4; ++i)
      #pragma unroll
      for (int j = 0; j < 4; ++j)
        #pragma unroll
        for (int r = 0; r < 4; ++r){
          const int m = m0 + wm*64 + i*16 + ((lane >> 4) << 2) + r;
          const int n = n0 + wn*64 + j*16 + (lane & 15);
          const float v  = acc[i][j][r];
          const float vp = __shfl_xor(v, 1, 64);
          const int sp = m & 2047, d = n & 63;
          const float2 cs = ((const float2*)tab)[sp*32 + (d >> 1)];
          const float o = ((n & 1) ? (cs.y*vp + cs.x*v) : (cs.x*v - cs.y*vp)) * scale;
          const int b = m >> 11, hh = n >> 6;
          *(__bf16*)&Dh[((size_t)((b*NH + hh)*SEQ + sp))*DK + d] = (__bf16)o;
        }
  } else {
    #pragma unroll
    for (int i = 0; i < 4; ++i)
      #pragma unroll
      for (int j = 0; j < 4; ++j)
        #pragma unroll
        for (int r = 0; r < 4; ++r){
          const int m = m0 + wm*64 + i*16 + ((lane >> 4) << 2) + r;
          const int n = n0 + wn*64 + j*16 + (lane & 15);
          if (MODE == 0){
            const int b = m >> 11, sp = m & 2047, hh = n >> 6, d = n & 63;
            *(__bf16*)&Dh[(((size_t)(b*NH + hh))*DK + d)*SEQ + sp] = (__bf16)acc[i][j][r];
          } else {
            Dout[(size_t)m * DM + n] = acc[i][j][r];
          }
        }
  }
}

// ============================================================
// Causal flash attention — swapped-QK^T 32x32 in-register softmax,
// kv-split dual-group blocks (8 waves, 512 threads), STATIC-MAX.
// (frozen from R9 — 0.0166 absmax validated)
// ============================================================
__global__ __launch_bounds__(512, 4) void k_attn(const unsigned short* __restrict__ Qh,
                                                 const unsigned short* __restrict__ Kh,
                                                 const unsigned short* __restrict__ Vt,
                                                 unsigned short* __restrict__ Ab)
{
  __shared__ uint4 ldsu[4096];   // 64 KiB: per-group [K0 8K|V0 8K][K1 8K|V1 8K]
  char* base = (char*)ldsu;
  const int tid  = threadIdx.x;
  const int lane = tid & 63;
  const int w    = tid >> 6;     // 0..7
  const int ww   = w & 3;        // wave-in-group
  const int g    = w >> 2;       // kv-half group
  const int tl   = tid & 255;    // thread-in-group
  const int l31  = lane & 31;
  const int hl   = lane >> 5;
  char* gb = base + g*32768;

  const int jj = blockIdx.x, bh = blockIdx.y;
  const unsigned short* Qb = Qh + (size_t)bh*(SEQ*DK);
  const unsigned short* Kb = Kh + (size_t)bh*(SEQ*DK);
  const unsigned short* Vb = Vt + (size_t)bh*(SEQ*DK);
  const int b = bh >> 4, hd = bh & 15;

  for (int pass = 0; pass < 2; ++pass){
    const int qt = pass ? jj : 15 - jj;
    const int q0 = qt * 128;
    const int qbase = q0 + ww*32;

    // Q as B-operand: n=q=lane&31, k-elems d = 16t + 8*hl + e
    bf16x8 qf[4];
    #pragma unroll
    for (int t = 0; t < 4; ++t)
      qf[t] = *(const bf16x8*)(Qb + (size_t)(qbase + l31)*DK + t*16 + hl*8);

    f32x16 acc0 = (f32x16)0.0f, acc1 = (f32x16)0.0f;
    float lsum = 0.0f;

    const int nk = qt + 1;           // tiles per group
    const int tbase = g * nk;        // group's first kv-tile
    const int wqmax = qbase + 31;

    auto stage = [&](int buf, int ktile){
      const int k0s = ktile * 64;
      char* Kd = gb + buf*16384;
      char* Vd = Kd + 8192;
      #pragma unroll
      for (int cc = 0; cc < 2; ++cc){
        const int f = cc*256 + tl;
        const int r = f >> 3, slot = f & 7;
        const int sw = ((slot ^ (r & 7)) << 3);     // element offset of 16B chunk
        gload16(Kb + (size_t)(k0s + r)*DK + sw, Kd + (cc*256 + ww*64)*16);
        gload16(Vb + (size_t)r*SEQ + k0s + sw, Vd + (cc*256 + ww*64)*16);
      }
    };

    if (pass) __syncthreads();     // LDS reuse across passes (also guards combine reads)
    stage(0, tbase);
    __syncthreads();               // drains vmcnt -> tile 0 visible
    int cur = 0;

    for (int kt = 0; kt < nk; ++kt){
      const int k0 = (tbase + kt) * 64;
      if (kt + 1 < nk) stage(cur ^ 1, tbase + kt + 1);   // prefetch overlaps compute
      if (k0 <= wqmax){
        const char* Ks = gb + cur*16384;
        const char* Vs = Ks + 8192;

        // ---- S^T = K Q^T (exp2 domain): sv[m] rows kv=32m+..., col q ----
        f32x16 sv0 = (f32x16)0.0f, sv1 = (f32x16)0.0f;
        #pragma unroll
        for (int t = 0; t < 4; ++t){
          const int colb = t*32 + hl*16;
          const bf16x8 a0 = ldsw(Ks, l31, colb);
          const bf16x8 a1 = ldsw(Ks, 32 + l31, colb);
          sv0 = __builtin_amdgcn_mfma_f32_32x32x16_bf16(a0, qf[t], sv0, 0, 0, 0);
          sv1 = __builtin_amdgcn_mfma_f32_32x32x16_bf16(a1, qf[t], sv1, 0, 0, 0);
        }

        // ---- causal mask (diagonal tiles only) ----
        if (k0 + 63 > qbase){
          const int q = qbase + l31;
          #pragma unroll
          for (int j = 0; j < 16; ++j){
            const int kv = k0 + (j&3) + 8*(j>>2) + 4*hl;
            if (kv > q)      sv0[j] = -1e30f;
            if (kv + 32 > q) sv1[j] = -1e30f;
          }
        }

        // ---- static-max softmax: P = exp2(S) directly ----
        #pragma unroll
        for (int j = 0; j < 16; ++j){
          sv0[j] = exp2f(sv0[j]);
          sv1[j] = exp2f(sv1[j]);
        }
        float ts[8];
        #pragma unroll
        for (int j = 0; j < 8; ++j)
          ts[j] = (sv0[j] + sv0[j+8]) + (sv1[j] + sv1[j+8]);
        #pragma unroll
        for (int off = 4; off; off >>= 1)
          #pragma unroll
          for (int j = 0; j < off; ++j)
            ts[j] += ts[j+off];
        lsum += ts[0] + __shfl_xor(ts[0], 32, 64);

        // ---- O^T += V^T P : P quads redistributed via cvt_pk + shfl(32) ----
        #pragma unroll
        for (int t = 0; t < 4; ++t){
          f32x16& s = (t < 2) ? sv0 : sv1;
          const int b0v = (t & 1) * 8;
          const unsigned int A0 = cvtpk(s[b0v+0], s[b0v+1]);
          const unsigned int A1 = cvtpk(s[b0v+2], s[b0v+3]);
          const unsigned int B0 = cvtpk(s[b0v+4], s[b0v+5]);
          const unsigned int B1 = cvtpk(s[b0v+6], s[b0v+7]);
          const unsigned int s0 = hl ? A0 : B0;
          const unsigned int s1 = hl ? A1 : B1;
          const unsigned int r0 = (unsigned int)__shfl_xor((int)s0, 32, 64);
          const unsigned int r1 = (unsigned int)__shfl_xor((int)s1, 32, 64);
          union { unsigned int u[4]; bf16x8 v; } f;
          f.u[0] = hl ? r0 : A0; f.u[1] = hl ? r1 : A1;
          f.u[2] = hl ? B0 : r0; f.u[3] = hl ? B1 : r1;
          const int colb = t*32 + hl*16;
          const bf16x8 v0 = ldsw(Vs, l31, colb);
          const bf16x8 v1 = ldsw(Vs, 32 + l31, colb);
          acc0 = __builtin_amdgcn_mfma_f32_32x32x16_bf16(v0, f.v, acc0, 0, 0, 0);
          acc1 = __builtin_amdgcn_mfma_f32_32x32x16_bf16(v1, f.v, acc1, 0, 0, 0);
        }
      }
      __syncthreads();             // compute done + prefetch vmcnt drained
      cur ^= 1;
    }

    // ---- combine halves: group1 -> LDS, group0 merges + stores ----
    if (g == 1){
      char* cw = base + ww*9216 + lane*144;
      #pragma unroll
      for (int q4 = 0; q4 < 4; ++q4){
        *(f32x4*)(cw + q4*16)      = (f32x4){acc0[4*q4], acc0[4*q4+1], acc0[4*q4+2], acc0[4*q4+3]};
        *(f32x4*)(cw + 64 + q4*16) = (f32x4){acc1[4*q4], acc1[4*q4+1], acc1[4*q4+2], acc1[4*q4+3]};
      }
      *(float*)(cw + 128) = lsum;
    }
    __syncthreads();
    if (g == 0){
      const char* cr = base + ww*9216 + lane*144;
      const float l1 = *(const float*)(cr + 128);
      const float linv = 1.0f / (lsum + l1);
      unsigned short* orow = Ab + ((size_t)(b*SEQ + qbase + l31))*DM + hd*DK;
      #pragma unroll
      for (int mt = 0; mt < 2; ++mt){
        #pragma unroll
        for (int g4 = 0; g4 < 4; ++g4){
          const f32x16& a = mt ? acc1 : acc0;
          const f32x4 o = *(const f32x4*)(cr + mt*64 + g4*16);
          const unsigned int u0 = cvtpk((a[4*g4+0] + o[0])*linv, (a[4*g4+1] + o[1])*linv);
          const unsigned int u1 = cvtpk((a[4*g4+2] + o[2])*linv, (a[4*g4+3] + o[3])*linv);
          *(unsigned long long*)(orow + mt*32 + g4*8 + hl*4) =
              (unsigned long long)u0 | ((unsigned long long)u1 << 32);
        }
      }
    }
  }
}

// ============================================================
// launch
// ============================================================
extern "C" void kernel_launch(void* const* d_in, const int* in_sizes, int n_in,
                              void* d_out, int out_size, void* d_ws, size_t ws_size,
                              hipStream_t stream)
{
  (void)in_sizes; (void)n_in; (void)out_size;
  const float* x  = (const float*)d_in[0];
  const float* wq = (const float*)d_in[1];
  const float* wk = (const float*)d_in[2];
  const float* wv = (const float*)d_in[3];
  const float* wo = (const float*)d_in[4];
  const int* pos  = (const int*)d_in[5];
  float* out = (float*)d_out;

  // workspace layout (bytes); Ab (attn out) aliases xb (x no longer needed)
  if (ws_size < 92800000u) return;   // need ~88.5 MB
  char* ws = (char*)d_ws;
  unsigned short* xb = (unsigned short*)(ws);                 // 16 MB (also Ab)
  unsigned short* wb = (unsigned short*)(ws + 16777216);      //  8 MB (Wq|Wk|Wv|Wo)
  unsigned short* Qh = (unsigned short*)(ws + 25165824);      // 16 MB [b][h][s][d]
  unsigned short* Kh = (unsigned short*)(ws + 41943040);      // 16 MB
  unsigned short* Vt = (unsigned short*)(ws + 75497472);      // 16 MB [b][h][d][s]
  float* tab         = (float*)(ws + 92274688);               // 512 KB

  k_tables  <<<256, 256, 0, stream>>>(pos, tab);
  k_convert <<<12288, 256, 0, stream>>>(x, wq, wk, wv, wo, xb, wb);
  k_gemm<0> <<<dim3(32, 8, 3), 512, 0, stream>>>(xb, wb, Qh, Kh, Vt, nullptr, tab);
  k_attn    <<<dim3(8, 64), 512, 0, stream>>>(Qh, Kh, Vt, xb);
  k_gemm<1> <<<dim3(32, 8, 1), 512, 0, stream>>>(xb, wb + 3*NW, nullptr, nullptr,
                                                 nullptr, out, nullptr);
}

// Round 11
// 188.492 us; speedup vs baseline: 1.0330x; 1.0330x over previous
//
#include <hip/hip_runtime.h>
#include <stdint.h>

// ---------- types ----------
typedef __attribute__((ext_vector_type(8))) __bf16 bf16x8;
typedef __attribute__((ext_vector_type(4))) float f32x4;
typedef __attribute__((ext_vector_type(16))) float f32x16;
typedef __attribute__((ext_vector_type(8))) unsigned short ushort8;

// ---------- helpers ----------
__device__ __forceinline__ unsigned short f2bf(float f){
  union { float f; unsigned int i; } v; v.f = f;
  unsigned int r = v.i + 0x7fffu + ((v.i >> 16) & 1u);   // RNE
  return (unsigned short)(r >> 16);
}
__device__ __forceinline__ void gload16(const void* g, void* l){
  __builtin_amdgcn_global_load_lds((__attribute__((address_space(1))) void*)(g),
                                   (__attribute__((address_space(3))) void*)(l),
                                   16, 0, 0);
}
__device__ __forceinline__ unsigned int cvtpk(float lo, float hi){
  unsigned int r;
  asm("v_cvt_pk_bf16_f32 %0, %1, %2" : "=v"(r) : "v"(lo), "v"(hi));
  return r;
}
// swizzled LDS read of a 16B chunk from a [64][64] bf16 tile (128B rows)
__device__ __forceinline__ bf16x8 ldsw(const char* tile, int row, int colb){
  return *(const bf16x8*)(tile + row*128 + (colb ^ ((row & 7) << 4)));
}

// ---------- constants ----------
#define SEQ   2048
#define DM    1024
#define NH    16
#define DK    64
#define BATCH 4
#define MTOT  (BATCH*SEQ)          // 8192
#define NX    (MTOT*DM)            // 8388608 elements in x
#define NW    (DM*DM)              // 1048576 per weight

#define QSCALE 0.18033688011112f   // (1/8) * log2(e)  -> softmax in exp2 domain

// ============================================================
// sin/cos table: tab[s*32+i] = {cos, sin} of pos[s]*theta^(-2i/64)
// ============================================================
__global__ __launch_bounds__(256) void k_tables(const int* __restrict__ pos,
                                                float* __restrict__ tab)
{
  const int idx = blockIdx.x * 256 + threadIdx.x;    // 65536 total
  const int s = idx >> 5, i = idx & 31;
  const float inv = __expf(-0.28782313662425575f * (float)i);
  const float a = (float)pos[s] * inv;
  tab[2*idx]   = cosf(a);
  tab[2*idx+1] = sinf(a);
}

// ============================================================
// fp32 -> bf16 convert: x (8.4M) then Wq,Wk,Wv,Wo (1M each)
// ============================================================
__global__ __launch_bounds__(256) void k_convert(
    const float* __restrict__ x,  const float* __restrict__ wq,
    const float* __restrict__ wk, const float* __restrict__ wv,
    const float* __restrict__ wo,
    unsigned short* __restrict__ xb, unsigned short* __restrict__ wb)
{
  const long long tid = (long long)blockIdx.x * 256 + threadIdx.x;
  const long long e = tid * 4;
  const float* src; unsigned short* dst;
  if (e < NX) { src = x + e; dst = xb + e; }
  else {
    long long j = e - NX;
    int seg = (int)(j >> 20);            // /1048576
    long long off = j & 1048575;
    src = (seg==0?wq:seg==1?wk:seg==2?wv:wo) + off;
    dst = wb + (size_t)seg*NW + off;
  }
  float4 v = *(const float4*)src;
  unsigned long long pk =  (unsigned long long)f2bf(v.x)
                        | ((unsigned long long)f2bf(v.y) << 16)
                        | ((unsigned long long)f2bf(v.z) << 32)
                        | ((unsigned long long)f2bf(v.w) << 48);
  *(unsigned long long*)dst = pk;
}

// ============================================================
// NT GEMM: C[M=8192][N] = A[M][K=1024] * W[N][K]^T  (bf16 MFMA)
// 256x128 tile, BK=32, 8 waves (4M x 2N), per-wave 64x64 output.
// 2-phase double-buffered global_load_lds staging (R9 structure).
// T2 LDS swizzle: 16B-chunk position ^= (row>>1)&3 — kills the
// 8-way bank aliasing of fragment ds_read_b128 (lanes 0-15 read 16
// different 64B rows at the same column). Applied per rule #21:
// linear LDS dest + pre-swizzled GLOBAL source + swizzled read.
// ============================================================
#define BK 32
#define NTK (DM/BK)   // 32

template<int MODE>
__global__ __launch_bounds__(512, 3) void k_gemm(
    const unsigned short* __restrict__ A,
    const unsigned short* __restrict__ Wb,
    unsigned short* __restrict__ D0,
    unsigned short* __restrict__ D1,
    unsigned short* __restrict__ D2,
    float* __restrict__ Dout,
    const float* __restrict__ tab)
{
  __shared__ __attribute__((aligned(16))) unsigned short As[2][256*BK];  // 32 KB
  __shared__ __attribute__((aligned(16))) unsigned short Bs[2][128*BK];  // 16 KB
  const int tid  = threadIdx.x;
  const int lane = tid & 63;
  const int w    = tid >> 6;          // 0..7
  const int wm = w >> 1, wn = w & 1;  // 4M x 2N
  const int m0 = blockIdx.x * 256;
  const int n0 = blockIdx.y * 128;

  const int z = (MODE == 0) ? blockIdx.z : 0;
  const unsigned short* W = Wb + (size_t)z * NW;
  unsigned short* Dh = (MODE == 0) ? ((z == 0) ? D0 : (z == 1) ? D1 : D2) : nullptr;
  const bool vtr = (MODE == 0) && (z == 2);

  f32x4 acc[4][4];
  #pragma unroll
  for (int i = 0; i < 4; ++i)
    #pragma unroll
    for (int j = 0; j < 4; ++j)
      acc[i][j] = (f32x4)0.0f;

  auto stage = [&](int buf, int t){
    const int k0 = t * BK;
    #pragma unroll
    for (int cc = 0; cc < 2; ++cc){
      const int f = cc*512 + tid;
      const int row = f >> 2, kc = f & 3;
      const int kcs = kc ^ ((row >> 1) & 3);          // pre-swizzled source chunk
      gload16(A + (size_t)(m0 + row)*DM + k0 + kcs*8,
              (char*)&As[buf][0] + (cc*512 + w*64)*16);
    }
    {
      const int row = tid >> 2, kc = tid & 3;
      const int kcs = kc ^ ((row >> 1) & 3);
      gload16(W + (size_t)(n0 + row)*DM + k0 + kcs*8,
              (char*)&Bs[buf][0] + (w*64)*16);
    }
  };

  stage(0, 0);
  __syncthreads();
  int cur = 0;
  for (int t = 0; t < NTK; ++t){
    if (t + 1 < NTK) stage(cur ^ 1, t + 1);
    const char* Ab_ = (const char*)&As[cur][0];
    const char* Bb_ = (const char*)&Bs[cur][0];
    bf16x8 af[4], bfr[4];
    #pragma unroll
    for (int i = 0; i < 4; ++i){
      const int rowA = wm*64 + i*16 + (lane & 15);
      const int rowB = wn*64 + i*16 + (lane & 15);
      af[i]  = *(const bf16x8*)(Ab_ + rowA*64 + ((((lane >> 4) ^ (rowA >> 1)) & 3) << 4));
      bfr[i] = *(const bf16x8*)(Bb_ + rowB*64 + ((((lane >> 4) ^ (rowB >> 1)) & 3) << 4));
    }
    #pragma unroll
    for (int i = 0; i < 4; ++i)
      #pragma unroll
      for (int j = 0; j < 4; ++j)
        acc[i][j] = __builtin_amdgcn_mfma_f32_16x16x32_bf16(af[i], bfr[j], acc[i][j], 0, 0, 0);
    __syncthreads();
    cur ^= 1;
  }

  // epilogue: C row = (lane>>4)*4+r, col = lane&15 (verified m89/m91 layout)
  if (MODE == 0 && !vtr){
    const float scale = (z == 0) ? QSCALE : 1.0f;
    #pragma unroll
    for (int i = 0; i < 4; ++i)
      #pragma unroll
      for (int j = 0; j < 4; ++j)
        #pragma unroll
        for (int r = 0; r < 4; ++r){
          const int m = m0 + wm*64 + i*16 + ((lane >> 4) << 2) + r;
          const int n = n0 + wn*64 + j*16 + (lane & 15);
          const float v  = acc[i][j][r];
          const float vp = __shfl_xor(v, 1, 64);
          const int sp = m & 2047, d = n & 63;
          const float2 cs = ((const float2*)tab)[sp*32 + (d >> 1)];
          const float o = ((n & 1) ? (cs.y*vp + cs.x*v) : (cs.x*v - cs.y*vp)) * scale;
          const int b = m >> 11, hh = n >> 6;
          *(__bf16*)&Dh[((size_t)((b*NH + hh)*SEQ + sp))*DK + d] = (__bf16)o;
        }
  } else {
    #pragma unroll
    for (int i = 0; i < 4; ++i)
      #pragma unroll
      for (int j = 0; j < 4; ++j)
        #pragma unroll
        for (int r = 0; r < 4; ++r){
          const int m = m0 + wm*64 + i*16 + ((lane >> 4) << 2) + r;
          const int n = n0 + wn*64 + j*16 + (lane & 15);
          if (MODE == 0){
            const int b = m >> 11, sp = m & 2047, hh = n >> 6, d = n & 63;
            *(__bf16*)&Dh[(((size_t)(b*NH + hh))*DK + d)*SEQ + sp] = (__bf16)acc[i][j][r];
          } else {
            Dout[(size_t)m * DM + n] = acc[i][j][r];
          }
        }
  }
}

// ============================================================
// Causal flash attention — swapped-QK^T 32x32 in-register softmax,
// kv-split dual-group blocks (8 waves, 512 threads), STATIC-MAX.
// (frozen from R9 — 0.0166 absmax validated)
// ============================================================
__global__ __launch_bounds__(512, 4) void k_attn(const unsigned short* __restrict__ Qh,
                                                 const unsigned short* __restrict__ Kh,
                                                 const unsigned short* __restrict__ Vt,
                                                 unsigned short* __restrict__ Ab)
{
  __shared__ uint4 ldsu[4096];   // 64 KiB: per-group [K0 8K|V0 8K][K1 8K|V1 8K]
  char* base = (char*)ldsu;
  const int tid  = threadIdx.x;
  const int lane = tid & 63;
  const int w    = tid >> 6;     // 0..7
  const int ww   = w & 3;        // wave-in-group
  const int g    = w >> 2;       // kv-half group
  const int tl   = tid & 255;    // thread-in-group
  const int l31  = lane & 31;
  const int hl   = lane >> 5;
  char* gb = base + g*32768;

  const int jj = blockIdx.x, bh = blockIdx.y;
  const unsigned short* Qb = Qh + (size_t)bh*(SEQ*DK);
  const unsigned short* Kb = Kh + (size_t)bh*(SEQ*DK);
  const unsigned short* Vb = Vt + (size_t)bh*(SEQ*DK);
  const int b = bh >> 4, hd = bh & 15;

  for (int pass = 0; pass < 2; ++pass){
    const int qt = pass ? jj : 15 - jj;
    const int q0 = qt * 128;
    const int qbase = q0 + ww*32;

    // Q as B-operand: n=q=lane&31, k-elems d = 16t + 8*hl + e
    bf16x8 qf[4];
    #pragma unroll
    for (int t = 0; t < 4; ++t)
      qf[t] = *(const bf16x8*)(Qb + (size_t)(qbase + l31)*DK + t*16 + hl*8);

    f32x16 acc0 = (f32x16)0.0f, acc1 = (f32x16)0.0f;
    float lsum = 0.0f;

    const int nk = qt + 1;           // tiles per group
    const int tbase = g * nk;        // group's first kv-tile
    const int wqmax = qbase + 31;

    auto stage = [&](int buf, int ktile){
      const int k0s = ktile * 64;
      char* Kd = gb + buf*16384;
      char* Vd = Kd + 8192;
      #pragma unroll
      for (int cc = 0; cc < 2; ++cc){
        const int f = cc*256 + tl;
        const int r = f >> 3, slot = f & 7;
        const int sw = ((slot ^ (r & 7)) << 3);     // element offset of 16B chunk
        gload16(Kb + (size_t)(k0s + r)*DK + sw, Kd + (cc*256 + ww*64)*16);
        gload16(Vb + (size_t)r*SEQ + k0s + sw, Vd + (cc*256 + ww*64)*16);
      }
    };

    if (pass) __syncthreads();     // LDS reuse across passes (also guards combine reads)
    stage(0, tbase);
    __syncthreads();               // drains vmcnt -> tile 0 visible
    int cur = 0;

    for (int kt = 0; kt < nk; ++kt){
      const int k0 = (tbase + kt) * 64;
      if (kt + 1 < nk) stage(cur ^ 1, tbase + kt + 1);   // prefetch overlaps compute
      if (k0 <= wqmax){
        const char* Ks = gb + cur*16384;
        const char* Vs = Ks + 8192;

        // ---- S^T = K Q^T (exp2 domain): sv[m] rows kv=32m+..., col q ----
        f32x16 sv0 = (f32x16)0.0f, sv1 = (f32x16)0.0f;
        #pragma unroll
        for (int t = 0; t < 4; ++t){
          const int colb = t*32 + hl*16;
          const bf16x8 a0 = ldsw(Ks, l31, colb);
          const bf16x8 a1 = ldsw(Ks, 32 + l31, colb);
          sv0 = __builtin_amdgcn_mfma_f32_32x32x16_bf16(a0, qf[t], sv0, 0, 0, 0);
          sv1 = __builtin_amdgcn_mfma_f32_32x32x16_bf16(a1, qf[t], sv1, 0, 0, 0);
        }

        // ---- causal mask (diagonal tiles only) ----
        if (k0 + 63 > qbase){
          const int q = qbase + l31;
          #pragma unroll
          for (int j = 0; j < 16; ++j){
            const int kv = k0 + (j&3) + 8*(j>>2) + 4*hl;
            if (kv > q)      sv0[j] = -1e30f;
            if (kv + 32 > q) sv1[j] = -1e30f;
          }
        }

        // ---- static-max softmax: P = exp2(S) directly ----
        #pragma unroll
        for (int j = 0; j < 16; ++j){
          sv0[j] = exp2f(sv0[j]);
          sv1[j] = exp2f(sv1[j]);
        }
        float ts[8];
        #pragma unroll
        for (int j = 0; j < 8; ++j)
          ts[j] = (sv0[j] + sv0[j+8]) + (sv1[j] + sv1[j+8]);
        #pragma unroll
        for (int off = 4; off; off >>= 1)
          #pragma unroll
          for (int j = 0; j < off; ++j)
            ts[j] += ts[j+off];
        lsum += ts[0] + __shfl_xor(ts[0], 32, 64);

        // ---- O^T += V^T P : P quads redistributed via cvt_pk + shfl(32) ----
        #pragma unroll
        for (int t = 0; t < 4; ++t){
          f32x16& s = (t < 2) ? sv0 : sv1;
          const int b0v = (t & 1) * 8;
          const unsigned int A0 = cvtpk(s[b0v+0], s[b0v+1]);
          const unsigned int A1 = cvtpk(s[b0v+2], s[b0v+3]);
          const unsigned int B0 = cvtpk(s[b0v+4], s[b0v+5]);
          const unsigned int B1 = cvtpk(s[b0v+6], s[b0v+7]);
          const unsigned int s0 = hl ? A0 : B0;
          const unsigned int s1 = hl ? A1 : B1;
          const unsigned int r0 = (unsigned int)__shfl_xor((int)s0, 32, 64);
          const unsigned int r1 = (unsigned int)__shfl_xor((int)s1, 32, 64);
          union { unsigned int u[4]; bf16x8 v; } f;
          f.u[0] = hl ? r0 : A0; f.u[1] = hl ? r1 : A1;
          f.u[2] = hl ? B0 : r0; f.u[3] = hl ? B1 : r1;
          const int colb = t*32 + hl*16;
          const bf16x8 v0 = ldsw(Vs, l31, colb);
          const bf16x8 v1 = ldsw(Vs, 32 + l31, colb);
          acc0 = __builtin_amdgcn_mfma_f32_32x32x16_bf16(v0, f.v, acc0, 0, 0, 0);
          acc1 = __builtin_amdgcn_mfma_f32_32x32x16_bf16(v1, f.v, acc1, 0, 0, 0);
        }
      }
      __syncthreads();             // compute done + prefetch vmcnt drained
      cur ^= 1;
    }

    // ---- combine halves: group1 -> LDS, group0 merges + stores ----
    if (g == 1){
      char* cw = base + ww*9216 + lane*144;
      #pragma unroll
      for (int q4 = 0; q4 < 4; ++q4){
        *(f32x4*)(cw + q4*16)      = (f32x4){acc0[4*q4], acc0[4*q4+1], acc0[4*q4+2], acc0[4*q4+3]};
        *(f32x4*)(cw + 64 + q4*16) = (f32x4){acc1[4*q4], acc1[4*q4+1], acc1[4*q4+2], acc1[4*q4+3]};
      }
      *(float*)(cw + 128) = lsum;
    }
    __syncthreads();
    if (g == 0){
      const char* cr = base + ww*9216 + lane*144;
      const float l1 = *(const float*)(cr + 128);
      const float linv = 1.0f / (lsum + l1);
      unsigned short* orow = Ab + ((size_t)(b*SEQ + qbase + l31))*DM + hd*DK;
      #pragma unroll
      for (int mt = 0; mt < 2; ++mt){
        #pragma unroll
        for (int g4 = 0; g4 < 4; ++g4){
          const f32x16& a = mt ? acc1 : acc0;
          const f32x4 o = *(const f32x4*)(cr + mt*64 + g4*16);
          const unsigned int u0 = cvtpk((a[4*g4+0] + o[0])*linv, (a[4*g4+1] + o[1])*linv);
          const unsigned int u1 = cvtpk((a[4*g4+2] + o[2])*linv, (a[4*g4+3] + o[3])*linv);
          *(unsigned long long*)(orow + mt*32 + g4*8 + hl*4) =
              (unsigned long long)u0 | ((unsigned long long)u1 << 32);
        }
      }
    }
  }
}

// ============================================================
// launch
// ============================================================
extern "C" void kernel_launch(void* const* d_in, const int* in_sizes, int n_in,
                              void* d_out, int out_size, void* d_ws, size_t ws_size,
                              hipStream_t stream)
{
  (void)in_sizes; (void)n_in; (void)out_size;
  const float* x  = (const float*)d_in[0];
  const float* wq = (const float*)d_in[1];
  const float* wk = (const float*)d_in[2];
  const float* wv = (const float*)d_in[3];
  const float* wo = (const float*)d_in[4];
  const int* pos  = (const int*)d_in[5];
  float* out = (float*)d_out;

  // workspace layout (bytes); Ab (attn out) aliases xb (x no longer needed)
  if (ws_size < 92800000u) return;   // need ~88.5 MB
  char* ws = (char*)d_ws;
  unsigned short* xb = (unsigned short*)(ws);                 // 16 MB (also Ab)
  unsigned short* wb = (unsigned short*)(ws + 16777216);      //  8 MB (Wq|Wk|Wv|Wo)
  unsigned short* Qh = (unsigned short*)(ws + 25165824);      // 16 MB [b][h][s][d]
  unsigned short* Kh = (unsigned short*)(ws + 41943040);      // 16 MB
  unsigned short* Vt = (unsigned short*)(ws + 75497472);      // 16 MB [b][h][d][s]
  float* tab         = (float*)(ws + 92274688);               // 512 KB

  k_tables  <<<256, 256, 0, stream>>>(pos, tab);
  k_convert <<<12288, 256, 0, stream>>>(x, wq, wk, wv, wo, xb, wb);
  k_gemm<0> <<<dim3(32, 8, 3), 512, 0, stream>>>(xb, wb, Qh, Kh, Vt, nullptr, tab);
  k_attn    <<<dim3(8, 64), 512, 0, stream>>>(Qh, Kh, Vt, xb);
  k_gemm<1> <<<dim3(32, 8, 1), 512, 0, stream>>>(xb, wb + 3*NW, nullptr, nullptr,
                                                 nullptr, out, nullptr);
}